// Round 1
// 1303.982 us; speedup vs baseline: 1.0235x; 1.0235x over previous
//
#include <hip/hip_runtime.h>

// N=65536 nodes, K=6 slots, M=688 message width.
// out[n,m] = MLP( front-zero-padded msgs[n,:,m] ), plus timestamps passthrough.
// Memory-bound: ~0.63 GB live reads (avg 3.5/6 slots valid) + 0.18 GB writes.
// Roofline @6.3 TB/s achievable: ~129 us for the kernel proper.
//
// This revision: (1) timestamps passthrough fused into the kernel (one fewer
// dispatch in the timed graph); (2) non-temporal loads/stores on all
// stream-once traffic (msgs, out) -- no reuse exists, keep L2/L3 clean for
// counts + weights.

typedef __attribute__((ext_vector_type(4))) float f32x4;

static constexpr int NN  = 65536;
static constexpr int KK  = 6;
static constexpr int MM  = 688;
static constexpr int GPN = MM / 4;                 // 172 float4 column-groups per node
static constexpr int TOTAL_G = NN * GPN;           // 11,272,192 (= 44032 * 256 exactly)
static constexpr int MAIN_BLOCKS = TOTAL_G / 256;  // 44032 (exact, no tail)
static constexpr int TS_VEC = NN / 4;              // 16384 float4 of timestamps
static constexpr int TS_BLOCKS = TS_VEC / 256;     // 64

__global__ __launch_bounds__(256)
void mlp_msg_agg_kernel(const float* __restrict__ msgs,
                        const int*   __restrict__ counts,
                        const float* __restrict__ timestamps,
                        const float* __restrict__ W1, const float* __restrict__ b1,
                        const float* __restrict__ W2, const float* __restrict__ b2,
                        const float* __restrict__ W3, const float* __restrict__ b3,
                        float* __restrict__ out)
{
    const int bid = blockIdx.x;

    // ---- tail blocks: timestamps passthrough (fused, replaces hipMemcpyAsync) ----
    if (bid >= MAIN_BLOCKS) {
        const int t = (bid - MAIN_BLOCKS) * 256 + threadIdx.x;   // [0, 16384)
        const f32x4 v = __builtin_nontemporal_load((const f32x4*)timestamps + t);
        __builtin_nontemporal_store(v, (f32x4*)(out + (size_t)NN * MM) + t);
        return;
    }

    const int g = bid * 256 + threadIdx.x;
    const int n = g / GPN;                  // node
    const int j = g - n * GPN;              // float4 group within node

    // ---- weights: wave-uniform addresses -> scalar loads into SGPRs ----
    float w1[KK][3], bb1[3], w2[3][2], bb2[2], w3[2], bb3;
    #pragma unroll
    for (int k = 0; k < KK; ++k)
        #pragma unroll
        for (int c = 0; c < 3; ++c) w1[k][c] = W1[k * 3 + c];
    #pragma unroll
    for (int c = 0; c < 3; ++c) bb1[c] = b1[c];
    #pragma unroll
    for (int c = 0; c < 3; ++c)
        #pragma unroll
        for (int d = 0; d < 2; ++d) w2[c][d] = W2[c * 2 + d];
    #pragma unroll
    for (int d = 0; d < 2; ++d) bb2[d] = b2[d];
    #pragma unroll
    for (int d = 0; d < 2; ++d) w3[d] = W3[d];
    bb3 = b3[0];

    // ---- gather 6 slots x 4 columns; skip (never fetch) the zero-padded slots ----
    const int c_n = counts[n];              // 1..6
    const int kstart = KK - c_n;            // first valid slot
    const float* base = msgs + (size_t)n * (KK * MM) + j * 4;

    f32x4 v[KK];
    #pragma unroll
    for (int k = 0; k < KK; ++k) {
        f32x4 t = (f32x4){0.f, 0.f, 0.f, 0.f};
        if (k >= kstart)                    // predicated: masked lanes fetch nothing
            t = __builtin_nontemporal_load((const f32x4*)(base + k * MM));
        v[k] = t;
    }

    // ---- tiny MLP 6 -> 3 -> 2 -> 1, fully unrolled, per sub-column ----
    float res[4];
    #pragma unroll
    for (int s = 0; s < 4; ++s) {
        float h1[3];
        #pragma unroll
        for (int c = 0; c < 3; ++c) {
            float acc = bb1[c];
            #pragma unroll
            for (int k = 0; k < KK; ++k) acc = fmaf(v[k][s], w1[k][c], acc);
            h1[c] = fmaxf(acc, 0.f);
        }
        float h2[2];
        #pragma unroll
        for (int d = 0; d < 2; ++d) {
            float acc = bb2[d];
            #pragma unroll
            for (int c = 0; c < 3; ++c) acc = fmaf(h1[c], w2[c][d], acc);
            h2[d] = fmaxf(acc, 0.f);
        }
        res[s] = fmaf(h2[0], w3[0], fmaf(h2[1], w3[1], bb3));
    }

    const f32x4 o4 = (f32x4){res[0], res[1], res[2], res[3]};
    __builtin_nontemporal_store(o4, (f32x4*)(out + (size_t)n * MM + j * 4));
}

extern "C" void kernel_launch(void* const* d_in, const int* in_sizes, int n_in,
                              void* d_out, int out_size, void* d_ws, size_t ws_size,
                              hipStream_t stream) {
    const float* msgs       = (const float*)d_in[0];
    const int*   counts     = (const int*)  d_in[1];
    const float* timestamps = (const float*)d_in[2];
    const float* W1 = (const float*)d_in[3];
    const float* b1 = (const float*)d_in[4];
    const float* W2 = (const float*)d_in[5];
    const float* b2 = (const float*)d_in[6];
    const float* W3 = (const float*)d_in[7];
    const float* b3 = (const float*)d_in[8];
    float* out = (float*)d_out;

    const int blocks = MAIN_BLOCKS + TS_BLOCKS;   // 44096
    mlp_msg_agg_kernel<<<blocks, 256, 0, stream>>>(
        msgs, counts, timestamps, W1, b1, W2, b2, W3, b3, out);
}